// Round 2
// baseline (336.225 us; speedup 1.0000x reference)
//
#include <hip/hip_runtime.h>

// SpatialAttention B=4 HW=4096 C=256 NH=4 d=64 — f16 MFMA flash attention.
// R2: f16 prepass into d_ws + global_load_lds staging (XOR-swizzled, conflict-
// free unpadded LDS) + double-buffered K/V with static buffers (1 barrier/iter).

#define HW 4096
#define CCH 256
#define DH 64
#define NH 4
#define QTILE 128
#define KTILE 64
#define NKT (HW / KTILE)
#define P_STRIDE 68
#define LOG2E 1.44269504088896340736f

typedef __attribute__((ext_vector_type(8))) _Float16 half8;
typedef __attribute__((ext_vector_type(4))) _Float16 half4;
typedef __attribute__((ext_vector_type(4))) float floatx4;

typedef __attribute__((address_space(1))) const unsigned int gbl_u32;
typedef __attribute__((address_space(3))) unsigned int lds_u32;

__device__ __forceinline__ void gload_lds16(const void* g, void* l) {
    __builtin_amdgcn_global_load_lds((gbl_u32*)g, (lds_u32*)l, 16, 0, 0);
}

__device__ __forceinline__ floatx4 mfma16(half8 a, half8 b, floatx4 c) {
    return __builtin_amdgcn_mfma_f32_16x16x32_f16(a, b, c, 0, 0, 0);
}

// ---------- prepass A: Qhat/Khat [B*NH][HW][64] f16, scale*log2e folded into Q ----------
__global__ __launch_bounds__(256) void prepass_qk(
    const float* __restrict__ q_in, const float* __restrict__ k_in,
    const float* __restrict__ wq, const float* __restrict__ bq,
    const float* __restrict__ wk, const float* __restrict__ bk,
    _Float16* __restrict__ Qhat, _Float16* __restrict__ Khat)
{
    int i4 = blockIdx.x * 256 + threadIdx.x;
    int idx = i4 * 4;
    int b = idx >> 20;                 // HW*C = 2^20
    int rem = idx & ((1 << 20) - 1);
    int row = rem >> 8;
    int c = rem & 255;
    int h = c >> 6;
    int ch = c & 63;
    floatx4 q4 = *(const floatx4*)(q_in + idx);
    floatx4 k4 = *(const floatx4*)(k_in + idx);
    floatx4 wq4 = *(const floatx4*)(wq + c);
    floatx4 bq4 = *(const floatx4*)(bq + c);
    floatx4 wk4 = *(const floatx4*)(wk + c);
    floatx4 bk4 = *(const floatx4*)(bk + c);
    const float qsc = 0.125f * LOG2E;
    half4 qh, kh;
    qh[0] = (_Float16)((q4.x * wq4.x + bq4.x) * qsc);
    qh[1] = (_Float16)((q4.y * wq4.y + bq4.y) * qsc);
    qh[2] = (_Float16)((q4.z * wq4.z + bq4.z) * qsc);
    qh[3] = (_Float16)((q4.w * wq4.w + bq4.w) * qsc);
    kh[0] = (_Float16)(k4.x * wk4.x + bk4.x);
    kh[1] = (_Float16)(k4.y * wk4.y + bk4.y);
    kh[2] = (_Float16)(k4.z * wk4.z + bk4.z);
    kh[3] = (_Float16)(k4.w * wk4.w + bk4.w);
    size_t o = ((size_t)(b * NH + h) * HW + row) * DH + ch;
    *(half4*)(Qhat + o) = qh;
    *(half4*)(Khat + o) = kh;
}

// ---------- prepass B: Vthat [B*NH][64][HW] f16 (transposed) ----------
__global__ __launch_bounds__(256) void prepass_v(
    const float* __restrict__ v_in, const float* __restrict__ wv,
    const float* __restrict__ bv, _Float16* __restrict__ Vthat)
{
    __shared__ _Float16 Lt[64 * 68];
    int t = threadIdx.x;
    int key0 = blockIdx.x * 64;
    int bh = blockIdx.y;
    int b = bh >> 2, h = bh & 3;
    int c4 = (t & 15) * 4;
    floatx4 wv4 = *(const floatx4*)(wv + h * DH + c4);
    floatx4 bv4 = *(const floatx4*)(bv + h * DH + c4);
    #pragma unroll
    for (int p = 0; p < 4; ++p) {
        int key = p * 16 + (t >> 4);
        const float* vp = v_in + ((size_t)b * HW + key0 + key) * CCH + h * DH + c4;
        floatx4 v4 = *(const floatx4*)vp;
        half4 vh;
        vh[0] = (_Float16)(v4.x * wv4.x + bv4.x);
        vh[1] = (_Float16)(v4.y * wv4.y + bv4.y);
        vh[2] = (_Float16)(v4.z * wv4.z + bv4.z);
        vh[3] = (_Float16)(v4.w * wv4.w + bv4.w);
        *(half4*)(&Lt[key * 68 + c4]) = vh;
    }
    __syncthreads();
    #pragma unroll
    for (int p = 0; p < 2; ++p) {
        int ch = p * 32 + (t >> 3);
        int kg = (t & 7) * 8;
        half8 v8;
        #pragma unroll
        for (int j = 0; j < 8; ++j) v8[j] = Lt[(kg + j) * 68 + ch];
        *(half8*)(Vthat + ((size_t)bh * DH + ch) * HW + key0 + kg) = v8;
    }
}

// ---------- attention ----------
__launch_bounds__(512, 4)
__global__ void attn_kernel(
    const _Float16* __restrict__ Qhat, const _Float16* __restrict__ Khat,
    const _Float16* __restrict__ Vthat,
    const float* __restrict__ wp, const float* __restrict__ bp,
    float* __restrict__ out)
{
    // Unpadded, XOR-swizzled tiles: slot s of row r holds data group (s ^ (r&7)).
    __shared__ alignas(16) _Float16 Ksm0[KTILE * DH];
    __shared__ alignas(16) _Float16 Ksm1[KTILE * DH];
    __shared__ alignas(16) _Float16 Vsm0[DH * KTILE];
    __shared__ alignas(16) _Float16 Vsm1[DH * KTILE];
    __shared__ alignas(16) _Float16 Ps[8 * 16 * P_STRIDE];

    const int tid = threadIdx.x;
    const int wave = tid >> 6;
    const int lane = tid & 63;
    const int l15 = lane & 15;
    const int quad = lane >> 4;
    const int ksw = l15 & 7;

    const int qtile = blockIdx.x;
    const int bh = blockIdx.y;

    // Q A-frags: direct 16B loads (scale pre-folded)
    const int qrow = qtile * QTILE + wave * 16 + l15;
    const _Float16* qp = Qhat + ((size_t)bh * HW + qrow) * DH + quad * 8;
    const half8 qfrag0 = *(const half8*)(qp);
    const half8 qfrag1 = *(const half8*)(qp + 32);

    // per-lane staging addresses (swizzle in global address, LDS stays dense)
    const int srow = wave * 8 + (lane >> 3);   // key (for K) / ch (for V)
    const int sslot = lane & 7;
    const _Float16* kgp = Khat + ((size_t)bh * HW + srow) * DH
                          + ((sslot ^ (srow & 7)) * 8);
    const _Float16* vgp = Vthat + ((size_t)bh * DH + srow) * HW
                          + ((sslot ^ (srow & 7)) * 8);
    _Float16* myP = Ps + wave * 16 * P_STRIDE;

    floatx4 acc[4];
    float m_i[4], l_i[4];
    #pragma unroll
    for (int r = 0; r < 4; ++r) { m_i[r] = -1e30f; l_i[r] = 0.0f; }
    #pragma unroll
    for (int nt = 0; nt < 4; ++nt) { floatx4 z = {0.f,0.f,0.f,0.f}; acc[nt] = z; }

    #define STAGE(kt, KB, VB) do {                                        \
        gload_lds16(kgp + (size_t)(kt) * (KTILE * DH), &(KB)[wave * 512]); \
        gload_lds16(vgp + (size_t)(kt) * KTILE,        &(VB)[wave * 512]); \
    } while (0)

    #define COMPUTE(KB, VB) do {                                              \
        floatx4 S[4];                                                         \
        _Pragma("unroll")                                                     \
        for (int nt = 0; nt < 4; ++nt) {                                      \
            const _Float16* kr = &(KB)[(l15 + 16 * nt) * 64];                 \
            half8 kf0 = *(const half8*)(kr + ((quad ^ ksw) * 8));             \
            half8 kf1 = *(const half8*)(kr + (((4 + quad) ^ ksw) * 8));       \
            floatx4 s = {0.f, 0.f, 0.f, 0.f};                                 \
            s = mfma16(qfrag0, kf0, s);                                       \
            s = mfma16(qfrag1, kf1, s);                                       \
            S[nt] = s;                                                        \
        }                                                                     \
        float newm[4], alpha[4];                                              \
        _Pragma("unroll")                                                     \
        for (int r = 0; r < 4; ++r) {                                         \
            float rm = fmaxf(fmaxf(S[0][r], S[1][r]), fmaxf(S[2][r], S[3][r]));\
            rm = fmaxf(rm, __shfl_xor(rm, 1));                                \
            rm = fmaxf(rm, __shfl_xor(rm, 2));                                \
            rm = fmaxf(rm, __shfl_xor(rm, 4));                                \
            rm = fmaxf(rm, __shfl_xor(rm, 8));                                \
            float nm = fmaxf(m_i[r], rm);                                     \
            alpha[r] = __builtin_amdgcn_exp2f(m_i[r] - nm);                   \
            newm[r] = nm;                                                     \
        }                                                                     \
        _Pragma("unroll")                                                     \
        for (int nt = 0; nt < 4; ++nt) {                                      \
            _Pragma("unroll")                                                 \
            for (int r = 0; r < 4; ++r) {                                     \
                float p = __builtin_amdgcn_exp2f(S[nt][r] - newm[r]);         \
                S[nt][r] = p;                                                 \
                myP[(quad * 4 + r) * P_STRIDE + nt * 16 + l15] = (_Float16)p; \
            }                                                                 \
        }                                                                     \
        _Pragma("unroll")                                                     \
        for (int r = 0; r < 4; ++r) {                                         \
            float rs = S[0][r] + S[1][r] + S[2][r] + S[3][r];                 \
            rs += __shfl_xor(rs, 1);                                          \
            rs += __shfl_xor(rs, 2);                                          \
            rs += __shfl_xor(rs, 4);                                          \
            rs += __shfl_xor(rs, 8);                                          \
            l_i[r] = l_i[r] * alpha[r] + rs;                                  \
            m_i[r] = newm[r];                                                 \
            acc[0][r] *= alpha[r];                                            \
            acc[1][r] *= alpha[r];                                            \
            acc[2][r] *= alpha[r];                                            \
            acc[3][r] *= alpha[r];                                            \
        }                                                                     \
        _Pragma("unroll")                                                     \
        for (int c = 0; c < 2; ++c) {                                         \
            half8 pf = *(const half8*)(&myP[l15 * P_STRIDE + c * 32 + quad * 8]);\
            _Pragma("unroll")                                                 \
            for (int nt = 0; nt < 4; ++nt) {                                  \
                const _Float16* vr = &(VB)[(l15 + 16 * nt) * 64];             \
                half8 vf = *(const half8*)(vr + (((c * 4 + quad) ^ ksw) * 8));\
                acc[nt] = mfma16(pf, vf, acc[nt]);                            \
            }                                                                 \
        }                                                                     \
    } while (0)

    STAGE(0, Ksm0, Vsm0);
    for (int kt = 0; kt < NKT; kt += 2) {
        __syncthreads();
        if (kt + 1 < NKT) STAGE(kt + 1, Ksm1, Vsm1);
        COMPUTE(Ksm0, Vsm0);
        __syncthreads();
        if (kt + 2 < NKT) STAGE(kt + 2, Ksm0, Vsm0);
        COMPUTE(Ksm1, Vsm1);
    }

    // epilogue
    const int b = bh >> 2, h = bh & 3, ch0 = h * DH;
    float inv_l[4];
    #pragma unroll
    for (int r = 0; r < 4; ++r) inv_l[r] = 1.0f / l_i[r];
    const int orow0 = qtile * QTILE + wave * 16 + quad * 4;
    #pragma unroll
    for (int nt = 0; nt < 4; ++nt) {
        int ch = ch0 + nt * 16 + l15;
        float wpv = wp[ch], bpv = bp[ch];
        #pragma unroll
        for (int r = 0; r < 4; ++r) {
            float o = acc[nt][r] * inv_l[r];
            out[((size_t)b * HW + orow0 + r) * CCH + ch] = o * wpv + bpv;
        }
    }
    #undef STAGE
    #undef COMPUTE
}

extern "C" void kernel_launch(void* const* d_in, const int* in_sizes, int n_in,
                              void* d_out, int out_size, void* d_ws, size_t ws_size,
                              hipStream_t stream) {
    const float* q_in = (const float*)d_in[0];
    const float* k_in = (const float*)d_in[1];
    const float* v_in = (const float*)d_in[2];
    const float* wq = (const float*)d_in[3];
    const float* bq = (const float*)d_in[4];
    const float* wk = (const float*)d_in[5];
    const float* bk = (const float*)d_in[6];
    const float* wv = (const float*)d_in[7];
    const float* bv = (const float*)d_in[8];
    const float* wp = (const float*)d_in[9];
    const float* bp = (const float*)d_in[10];
    float* out = (float*)d_out;

    const size_t tensor_halves = (size_t)4 * NH * HW * DH;   // 4 Mi halves = 8 MB
    _Float16* Qhat = (_Float16*)d_ws;
    _Float16* Khat = Qhat + tensor_halves;
    _Float16* Vthat = Khat + tensor_halves;

    prepass_qk<<<dim3(4096), 256, 0, stream>>>(q_in, k_in, wq, bq, wk, bk, Qhat, Khat);
    prepass_v<<<dim3(64, 16), 256, 0, stream>>>(v_in, wv, bv, Vthat);
    attn_kernel<<<dim3(HW / QTILE, 4 * NH), 512, 0, stream>>>(
        Qhat, Khat, Vthat, wp, bp, out);
}

// Round 3
// 222.042 us; speedup vs baseline: 1.5142x; 1.5142x over previous
//
#include <hip/hip_runtime.h>

// SpatialAttention B=4 HW=4096 C=256 NH=4 d=64 — f16 MFMA flash attention.
// R3: transposed S^T=K·Q^T formulation (per-lane q-columns: softmax with only
// 2 cross-lane ops, b64-packed P writes), 32 q-rows/wave (K/V LDS reads halved
// per q), LDS-transposed epilogue. LDS-BW was the R2 bottleneck (~28KB/wave-iter).

#define HW 4096
#define CCH 256
#define DH 64
#define NH 4
#define QTILE 128
#define KTILE 64
#define NKT (HW / KTILE)
#define LOG2E 1.44269504088896340736f

typedef __attribute__((ext_vector_type(8))) _Float16 half8;
typedef __attribute__((ext_vector_type(4))) _Float16 half4;
typedef __attribute__((ext_vector_type(4))) float floatx4;

typedef __attribute__((address_space(1))) const unsigned int gbl_u32;
typedef __attribute__((address_space(3))) unsigned int lds_u32;

__device__ __forceinline__ void gload_lds16(const void* g, void* l) {
    __builtin_amdgcn_global_load_lds((gbl_u32*)g, (lds_u32*)l, 16, 0, 0);
}
__device__ __forceinline__ floatx4 mfma16(half8 a, half8 b, floatx4 c) {
    return __builtin_amdgcn_mfma_f32_16x16x32_f16(a, b, c, 0, 0, 0);
}

// ---------- prepass A: Qhat/Khat [B*NH][HW][64] f16, scale*log2e folded into Q ----------
__global__ __launch_bounds__(256) void prepass_qk(
    const float* __restrict__ q_in, const float* __restrict__ k_in,
    const float* __restrict__ wq, const float* __restrict__ bq,
    const float* __restrict__ wk, const float* __restrict__ bk,
    _Float16* __restrict__ Qhat, _Float16* __restrict__ Khat)
{
    int i4 = blockIdx.x * 256 + threadIdx.x;
    int idx = i4 * 4;
    int b = idx >> 20;
    int rem = idx & ((1 << 20) - 1);
    int row = rem >> 8;
    int c = rem & 255;
    int h = c >> 6;
    int ch = c & 63;
    floatx4 q4 = *(const floatx4*)(q_in + idx);
    floatx4 k4 = *(const floatx4*)(k_in + idx);
    floatx4 wq4 = *(const floatx4*)(wq + c);
    floatx4 bq4 = *(const floatx4*)(bq + c);
    floatx4 wk4 = *(const floatx4*)(wk + c);
    floatx4 bk4 = *(const floatx4*)(bk + c);
    const float qsc = 0.125f * LOG2E;
    half4 qh, kh;
    qh[0] = (_Float16)((q4.x * wq4.x + bq4.x) * qsc);
    qh[1] = (_Float16)((q4.y * wq4.y + bq4.y) * qsc);
    qh[2] = (_Float16)((q4.z * wq4.z + bq4.z) * qsc);
    qh[3] = (_Float16)((q4.w * wq4.w + bq4.w) * qsc);
    kh[0] = (_Float16)(k4.x * wk4.x + bk4.x);
    kh[1] = (_Float16)(k4.y * wk4.y + bk4.y);
    kh[2] = (_Float16)(k4.z * wk4.z + bk4.z);
    kh[3] = (_Float16)(k4.w * wk4.w + bk4.w);
    size_t o = ((size_t)(b * NH + h) * HW + row) * DH + ch;
    *(half4*)(Qhat + o) = qh;
    *(half4*)(Khat + o) = kh;
}

// ---------- prepass B: Vthat [B*NH][64][HW] f16 (transposed) ----------
__global__ __launch_bounds__(256) void prepass_v(
    const float* __restrict__ v_in, const float* __restrict__ wv,
    const float* __restrict__ bv, _Float16* __restrict__ Vthat)
{
    __shared__ _Float16 Lt[64 * 68];
    int t = threadIdx.x;
    int key0 = blockIdx.x * 64;
    int bh = blockIdx.y;
    int b = bh >> 2, h = bh & 3;
    int c4 = (t & 15) * 4;
    floatx4 wv4 = *(const floatx4*)(wv + h * DH + c4);
    floatx4 bv4 = *(const floatx4*)(bv + h * DH + c4);
    #pragma unroll
    for (int p = 0; p < 4; ++p) {
        int key = p * 16 + (t >> 4);
        const float* vp = v_in + ((size_t)b * HW + key0 + key) * CCH + h * DH + c4;
        floatx4 v4 = *(const floatx4*)vp;
        half4 vh;
        vh[0] = (_Float16)(v4.x * wv4.x + bv4.x);
        vh[1] = (_Float16)(v4.y * wv4.y + bv4.y);
        vh[2] = (_Float16)(v4.z * wv4.z + bv4.z);
        vh[3] = (_Float16)(v4.w * wv4.w + bv4.w);
        *(half4*)(&Lt[key * 68 + c4]) = vh;
    }
    __syncthreads();
    #pragma unroll
    for (int p = 0; p < 2; ++p) {
        int ch = p * 32 + (t >> 3);
        int kg = (t & 7) * 8;
        half8 v8;
        #pragma unroll
        for (int j = 0; j < 8; ++j) v8[j] = Lt[(kg + j) * 68 + ch];
        *(half8*)(Vthat + ((size_t)bh * DH + ch) * HW + key0 + kg) = v8;
    }
}

// ---------- attention (transposed formulation) ----------
__launch_bounds__(256, 3)
__global__ void attn_kernel(
    const _Float16* __restrict__ Qhat, const _Float16* __restrict__ Khat,
    const _Float16* __restrict__ Vthat,
    const float* __restrict__ wp, const float* __restrict__ bp,
    float* __restrict__ out)
{
    // pool: Ksm0 | Ksm1 | Vsm0 | Vsm1 (8KB each) | Pl (4 waves x 4608B)
    // epilogue reuses pool as per-wave Ot (wave*9216, 9216B each)
    __shared__ alignas(16) char pool[51200];
    _Float16* Ksm0 = (_Float16*)(pool);
    _Float16* Ksm1 = (_Float16*)(pool + 8192);
    _Float16* Vsm0 = (_Float16*)(pool + 16384);
    _Float16* Vsm1 = (_Float16*)(pool + 24576);

    const int tid = threadIdx.x;
    const int wave = tid >> 6;
    const int lane = tid & 63;
    const int l15 = lane & 15;
    const int quad = lane >> 4;
    const int ksw = l15 & 7;

    const int qtile = blockIdx.x;
    const int bh = blockIdx.y;

    _Float16* Pl = (_Float16*)(pool + 32768) + wave * 2304;   // [32 q][72]

    // Q B-frags (B[k=ch][n=q]): identical per-lane elements to old A-frags
    const int q0 = qtile * QTILE + wave * 32;
    half8 qfrag[2][2];
    #pragma unroll
    for (int g = 0; g < 2; ++g) {
        const _Float16* qp = Qhat + ((size_t)bh * HW + q0 + g * 16 + l15) * DH + quad * 8;
        qfrag[g][0] = *(const half8*)(qp);
        qfrag[g][1] = *(const half8*)(qp + 32);
    }

    // staging lane addresses (XOR swizzle in global addr; LDS dense)
    const int srow0 = lane >> 3;           // 0..7
    const int sw = (lane & 7) ^ srow0;
    const _Float16* kgp0 = Khat + ((size_t)bh * HW + wave * 8 + srow0) * DH + sw * 8;
    const _Float16* kgp1 = kgp0 + (size_t)32 * DH;
    const _Float16* vgp0 = Vthat + ((size_t)bh * DH + wave * 8 + srow0) * HW + sw * 8;
    const _Float16* vgp1 = vgp0 + (size_t)32 * HW;

    floatx4 acc[2][4];
    float m_i[2], l_i[2];
    #pragma unroll
    for (int g = 0; g < 2; ++g) {
        m_i[g] = -1e30f; l_i[g] = 0.0f;
        #pragma unroll
        for (int nt = 0; nt < 4; ++nt) { floatx4 z = {0.f,0.f,0.f,0.f}; acc[g][nt] = z; }
    }

    #define STAGE(kt, KB, VB) do {                                             \
        gload_lds16(kgp0 + (size_t)(kt) * (KTILE * DH), (KB) + wave * 512);    \
        gload_lds16(kgp1 + (size_t)(kt) * (KTILE * DH), (KB) + 2048 + wave * 512); \
        gload_lds16(vgp0 + (size_t)(kt) * KTILE, (VB) + wave * 512);           \
        gload_lds16(vgp1 + (size_t)(kt) * KTILE, (VB) + 2048 + wave * 512);    \
    } while (0)

    #define COMPUTE(KB, VB) do {                                               \
        floatx4 S[2][4];                                                       \
        _Pragma("unroll")                                                      \
        for (int kt = 0; kt < 4; ++kt) {                                       \
            const _Float16* kr = (KB) + (l15 + 16 * kt) * 64;                  \
            half8 kf0 = *(const half8*)(kr + ((quad ^ ksw) * 8));              \
            half8 kf1 = *(const half8*)(kr + (((4 + quad) ^ ksw) * 8));        \
            _Pragma("unroll")                                                  \
            for (int g = 0; g < 2; ++g) {                                      \
                floatx4 s = {0.f, 0.f, 0.f, 0.f};                              \
                s = mfma16(kf0, qfrag[g][0], s);                               \
                s = mfma16(kf1, qfrag[g][1], s);                               \
                S[g][kt] = s;                                                  \
            }                                                                  \
        }                                                                      \
        _Pragma("unroll")                                                      \
        for (int g = 0; g < 2; ++g) {                                          \
            float mx = fmaxf(fmaxf(fmaxf(S[g][0][0], S[g][0][1]),              \
                                   fmaxf(S[g][0][2], S[g][0][3])),             \
                             fmaxf(fmaxf(S[g][1][0], S[g][1][1]),              \
                                   fmaxf(S[g][1][2], S[g][1][3])));            \
            float mx2 = fmaxf(fmaxf(fmaxf(S[g][2][0], S[g][2][1]),             \
                                    fmaxf(S[g][2][2], S[g][2][3])),            \
                              fmaxf(fmaxf(S[g][3][0], S[g][3][1]),             \
                                    fmaxf(S[g][3][2], S[g][3][3])));           \
            mx = fmaxf(mx, mx2);                                               \
            mx = fmaxf(mx, __shfl_xor(mx, 16));                                \
            mx = fmaxf(mx, __shfl_xor(mx, 32));                                \
            float nm = fmaxf(m_i[g], mx);                                      \
            float alpha = __builtin_amdgcn_exp2f(m_i[g] - nm);                 \
            float rs = 0.0f;                                                   \
            _Pragma("unroll")                                                  \
            for (int kt = 0; kt < 4; ++kt) {                                   \
                half4 ph;                                                      \
                _Pragma("unroll")                                              \
                for (int r = 0; r < 4; ++r) {                                  \
                    float p = __builtin_amdgcn_exp2f(S[g][kt][r] - nm);        \
                    rs += p;                                                   \
                    ph[r] = (_Float16)p;                                       \
                }                                                              \
                *(half4*)(Pl + (g * 16 + l15) * 72 + kt * 16 + quad * 4) = ph; \
            }                                                                  \
            rs += __shfl_xor(rs, 16);                                          \
            rs += __shfl_xor(rs, 32);                                          \
            l_i[g] = l_i[g] * alpha + rs;                                      \
            m_i[g] = nm;                                                       \
            _Pragma("unroll")                                                  \
            for (int nt = 0; nt < 4; ++nt) acc[g][nt] *= alpha;                \
        }                                                                      \
        _Pragma("unroll")                                                      \
        for (int c = 0; c < 2; ++c) {                                          \
            half8 pf[2];                                                       \
            _Pragma("unroll")                                                  \
            for (int g = 0; g < 2; ++g)                                        \
                pf[g] = *(const half8*)(Pl + (g * 16 + l15) * 72 + c * 32 + quad * 8); \
            _Pragma("unroll")                                                  \
            for (int nt = 0; nt < 4; ++nt) {                                   \
                const _Float16* vr = (VB) + (l15 + 16 * nt) * 64;              \
                half8 vf = *(const half8*)(vr + (((c * 4 + quad) ^ ksw) * 8)); \
                _Pragma("unroll")                                              \
                for (int g = 0; g < 2; ++g)                                    \
                    acc[g][nt] = mfma16(vf, pf[g], acc[g][nt]);                \
            }                                                                  \
        }                                                                      \
    } while (0)

    STAGE(0, Ksm0, Vsm0);
    for (int kt = 0; kt < NKT; kt += 2) {
        __syncthreads();
        if (kt + 1 < NKT) STAGE(kt + 1, Ksm1, Vsm1);
        COMPUTE(Ksm0, Vsm0);
        __syncthreads();
        if (kt + 2 < NKT) STAGE(kt + 2, Ksm0, Vsm0);
        COMPUTE(Ksm1, Vsm1);
    }

    // ---- epilogue: transpose O^T through LDS, coalesced stores ----
    const int b = bh >> 2, h = bh & 3, ch0 = h * DH;
    floatx4 wp4 = *(const floatx4*)(wp + ch0 + l15 * 4);
    floatx4 bp4 = *(const floatx4*)(bp + ch0 + l15 * 4);
    float inv_l[2];
    #pragma unroll
    for (int g = 0; g < 2; ++g) inv_l[g] = 1.0f / l_i[g];

    __syncthreads();   // everyone done reading K/V/P before pool reuse
    float* Ot = (float*)(pool + wave * 9216);   // [32 q][72]
    #pragma unroll
    for (int g = 0; g < 2; ++g) {
        #pragma unroll
        for (int nt = 0; nt < 4; ++nt) {
            floatx4 o;
            #pragma unroll
            for (int r = 0; r < 4; ++r) o[r] = acc[g][nt][r] * inv_l[g];
            *(floatx4*)&Ot[(g * 16 + l15) * 72 + nt * 16 + quad * 4] = o;
        }
    }
    #pragma unroll
    for (int i = 0; i < 8; ++i) {
        int q = i * 4 + quad;
        floatx4 v = *(const floatx4*)&Ot[q * 72 + l15 * 4];
        floatx4 o;
        o.x = v.x * wp4.x + bp4.x;
        o.y = v.y * wp4.y + bp4.y;
        o.z = v.z * wp4.z + bp4.z;
        o.w = v.w * wp4.w + bp4.w;
        *(floatx4*)(out + ((size_t)b * HW + q0 + q) * CCH + ch0 + l15 * 4) = o;
    }
    #undef STAGE
    #undef COMPUTE
}

extern "C" void kernel_launch(void* const* d_in, const int* in_sizes, int n_in,
                              void* d_out, int out_size, void* d_ws, size_t ws_size,
                              hipStream_t stream) {
    const float* q_in = (const float*)d_in[0];
    const float* k_in = (const float*)d_in[1];
    const float* v_in = (const float*)d_in[2];
    const float* wq = (const float*)d_in[3];
    const float* bq = (const float*)d_in[4];
    const float* wk = (const float*)d_in[5];
    const float* bk = (const float*)d_in[6];
    const float* wv = (const float*)d_in[7];
    const float* bv = (const float*)d_in[8];
    const float* wp = (const float*)d_in[9];
    const float* bp = (const float*)d_in[10];
    float* out = (float*)d_out;

    const size_t tensor_halves = (size_t)4 * NH * HW * DH;
    _Float16* Qhat = (_Float16*)d_ws;
    _Float16* Khat = Qhat + tensor_halves;
    _Float16* Vthat = Khat + tensor_halves;

    prepass_qk<<<dim3(4096), 256, 0, stream>>>(q_in, k_in, wq, bq, wk, bk, Qhat, Khat);
    prepass_v<<<dim3(64, 16), 256, 0, stream>>>(v_in, wv, bv, Vthat);
    attn_kernel<<<dim3(HW / QTILE, 4 * NH), 256, 0, stream>>>(
        Qhat, Khat, Vthat, wp, bp, out);
}

// Round 5
// 210.582 us; speedup vs baseline: 1.5966x; 1.0544x over previous
//
#include <hip/hip_runtime.h>

// SpatialAttention B=4 HW=4096 C=256 NH=4 d=64 — f16 MFMA flash attention.
// R5 (= R4 + type fix): P kept in registers — PV uses v_mfma_f32_16x16x16_f16
// whose B-frag k-map (quad*4+j) equals the S-tile C/D row map (quad*4+r), so
// exp2 results are packed (cvt_pkrtz) and fed straight to MFMA. LDS/wave-iter
// 24->16KB, P round-trip latency + its bank conflicts removed. Prepasses fused.

#define HW 4096
#define CCH 256
#define DH 64
#define NH 4
#define QTILE 128
#define KTILE 64
#define NKT (HW / KTILE)
#define LOG2E 1.44269504088896340736f

typedef __attribute__((ext_vector_type(8))) _Float16 half8;
typedef __attribute__((ext_vector_type(4))) _Float16 half4;
typedef __attribute__((ext_vector_type(2))) __fp16 pk16x2;   // cvt_pkrtz native type
typedef __attribute__((ext_vector_type(4))) float floatx4;

typedef __attribute__((address_space(1))) const unsigned int gbl_u32;
typedef __attribute__((address_space(3))) unsigned int lds_u32;

__device__ __forceinline__ void gload_lds16(const void* g, void* l) {
    __builtin_amdgcn_global_load_lds((gbl_u32*)g, (lds_u32*)l, 16, 0, 0);
}
__device__ __forceinline__ floatx4 mfma_k32(half8 a, half8 b, floatx4 c) {
    return __builtin_amdgcn_mfma_f32_16x16x32_f16(a, b, c, 0, 0, 0);
}
__device__ __forceinline__ floatx4 mfma_k16(half4 a, half4 b, floatx4 c) {
    return __builtin_amdgcn_mfma_f32_16x16x16f16(a, b, c, 0, 0, 0);
}

// ---------- fused prepass ----------
// blocks [0,4096): Qhat/Khat elementwise (scale*log2e folded into Q)
// blocks [4096,5120): Vthat transpose [B*NH][64][HW]
__global__ __launch_bounds__(256) void prepass_all(
    const float* __restrict__ q_in, const float* __restrict__ k_in,
    const float* __restrict__ v_in,
    const float* __restrict__ wq, const float* __restrict__ bq,
    const float* __restrict__ wk, const float* __restrict__ bk,
    const float* __restrict__ wv, const float* __restrict__ bv,
    _Float16* __restrict__ Qhat, _Float16* __restrict__ Khat,
    _Float16* __restrict__ Vthat)
{
    if (blockIdx.x < 4096) {
        int idx = (blockIdx.x * 256 + threadIdx.x) * 4;
        int b = idx >> 20;
        int rem = idx & ((1 << 20) - 1);
        int row = rem >> 8;
        int c = rem & 255;
        int h = c >> 6;
        int ch = c & 63;
        floatx4 q4 = *(const floatx4*)(q_in + idx);
        floatx4 k4 = *(const floatx4*)(k_in + idx);
        floatx4 wq4 = *(const floatx4*)(wq + c);
        floatx4 bq4 = *(const floatx4*)(bq + c);
        floatx4 wk4 = *(const floatx4*)(wk + c);
        floatx4 bk4 = *(const floatx4*)(bk + c);
        const float qsc = 0.125f * LOG2E;
        half4 qh, kh;
        qh[0] = (_Float16)((q4.x * wq4.x + bq4.x) * qsc);
        qh[1] = (_Float16)((q4.y * wq4.y + bq4.y) * qsc);
        qh[2] = (_Float16)((q4.z * wq4.z + bq4.z) * qsc);
        qh[3] = (_Float16)((q4.w * wq4.w + bq4.w) * qsc);
        kh[0] = (_Float16)(k4.x * wk4.x + bk4.x);
        kh[1] = (_Float16)(k4.y * wk4.y + bk4.y);
        kh[2] = (_Float16)(k4.z * wk4.z + bk4.z);
        kh[3] = (_Float16)(k4.w * wk4.w + bk4.w);
        size_t o = ((size_t)(b * NH + h) * HW + row) * DH + ch;
        *(half4*)(Qhat + o) = qh;
        *(half4*)(Khat + o) = kh;
    } else {
        __shared__ _Float16 Lt[64 * 68];
        int bx = blockIdx.x - 4096;
        int t = threadIdx.x;
        int key0 = (bx & 63) * 64;
        int bh = bx >> 6;
        int b = bh >> 2, h = bh & 3;
        int c4 = (t & 15) * 4;
        floatx4 wv4 = *(const floatx4*)(wv + h * DH + c4);
        floatx4 bv4 = *(const floatx4*)(bv + h * DH + c4);
        #pragma unroll
        for (int p = 0; p < 4; ++p) {
            int key = p * 16 + (t >> 4);
            const float* vp = v_in + ((size_t)b * HW + key0 + key) * CCH + h * DH + c4;
            floatx4 v4 = *(const floatx4*)vp;
            half4 vh;
            vh[0] = (_Float16)(v4.x * wv4.x + bv4.x);
            vh[1] = (_Float16)(v4.y * wv4.y + bv4.y);
            vh[2] = (_Float16)(v4.z * wv4.z + bv4.z);
            vh[3] = (_Float16)(v4.w * wv4.w + bv4.w);
            *(half4*)(&Lt[key * 68 + c4]) = vh;
        }
        __syncthreads();
        #pragma unroll
        for (int p = 0; p < 2; ++p) {
            int ch = p * 32 + (t >> 3);
            int kg = (t & 7) * 8;
            half8 v8;
            #pragma unroll
            for (int j = 0; j < 8; ++j) v8[j] = Lt[(kg + j) * 68 + ch];
            *(half8*)(Vthat + ((size_t)bh * DH + ch) * HW + key0 + kg) = v8;
        }
    }
}

// ---------- attention (transposed, register-P) ----------
__launch_bounds__(256, 3)
__global__ void attn_kernel(
    const _Float16* __restrict__ Qhat, const _Float16* __restrict__ Khat,
    const _Float16* __restrict__ Vthat,
    const float* __restrict__ wp, const float* __restrict__ bp,
    float* __restrict__ out)
{
    // pool: Ksm0 | Ksm1 | Vsm0 | Vsm1 (8KB each); epilogue reuses as Ot
    __shared__ alignas(16) char pool[36864];
    _Float16* Ksm0 = (_Float16*)(pool);
    _Float16* Ksm1 = (_Float16*)(pool + 8192);
    _Float16* Vsm0 = (_Float16*)(pool + 16384);
    _Float16* Vsm1 = (_Float16*)(pool + 24576);

    const int tid = threadIdx.x;
    const int wave = tid >> 6;
    const int lane = tid & 63;
    const int l15 = lane & 15;
    const int quad = lane >> 4;
    const int ksw = l15 & 7;

    const int qtile = blockIdx.x;
    const int bh = blockIdx.y;

    // Q B-frags: B[k=ch][n=q], lane holds ch = quad*8+j (+32), q = l15 (+16g)
    const int q0 = qtile * QTILE + wave * 32;
    half8 qfrag[2][2];
    #pragma unroll
    for (int g = 0; g < 2; ++g) {
        const _Float16* qp = Qhat + ((size_t)bh * HW + q0 + g * 16 + l15) * DH + quad * 8;
        qfrag[g][0] = *(const half8*)(qp);
        qfrag[g][1] = *(const half8*)(qp + 32);
    }

    // staging lane addresses (XOR swizzle of 8-half groups in global addr)
    const int srow0 = lane >> 3;
    const int sw = (lane & 7) ^ srow0;
    const _Float16* kgp0 = Khat + ((size_t)bh * HW + wave * 8 + srow0) * DH + sw * 8;
    const _Float16* kgp1 = kgp0 + (size_t)32 * DH;
    const _Float16* vgp0 = Vthat + ((size_t)bh * DH + wave * 8 + srow0) * HW + sw * 8;
    const _Float16* vgp1 = vgp0 + (size_t)32 * HW;

    floatx4 acc[2][4];
    float m_i[2], l_i[2];
    #pragma unroll
    for (int g = 0; g < 2; ++g) {
        m_i[g] = -1e30f; l_i[g] = 0.0f;
        #pragma unroll
        for (int nt = 0; nt < 4; ++nt) { floatx4 z = {0.f,0.f,0.f,0.f}; acc[g][nt] = z; }
    }

    #define STAGE(kt, KB, VB) do {                                             \
        gload_lds16(kgp0 + (size_t)(kt) * (KTILE * DH), (KB) + wave * 512);    \
        gload_lds16(kgp1 + (size_t)(kt) * (KTILE * DH), (KB) + 2048 + wave * 512); \
        gload_lds16(vgp0 + (size_t)(kt) * KTILE, (VB) + wave * 512);           \
        gload_lds16(vgp1 + (size_t)(kt) * KTILE, (VB) + 2048 + wave * 512);    \
    } while (0)

    #define COMPUTE(KB, VB) do {                                               \
        floatx4 S[2][4];                                                       \
        _Pragma("unroll")                                                      \
        for (int kt = 0; kt < 4; ++kt) {                                       \
            const _Float16* kr = (KB) + (l15 + 16 * kt) * 64;                  \
            half8 kf0 = *(const half8*)(kr + ((quad ^ ksw) * 8));              \
            half8 kf1 = *(const half8*)(kr + (((4 + quad) ^ ksw) * 8));        \
            _Pragma("unroll")                                                  \
            for (int g = 0; g < 2; ++g) {                                      \
                floatx4 s = {0.f, 0.f, 0.f, 0.f};                              \
                s = mfma_k32(kf0, qfrag[g][0], s);                             \
                s = mfma_k32(kf1, qfrag[g][1], s);                             \
                S[g][kt] = s;                                                  \
            }                                                                  \
        }                                                                      \
        half4 pfrag[2][4];                                                     \
        _Pragma("unroll")                                                      \
        for (int g = 0; g < 2; ++g) {                                          \
            float mx = fmaxf(fmaxf(fmaxf(S[g][0][0], S[g][0][1]),              \
                                   fmaxf(S[g][0][2], S[g][0][3])),             \
                             fmaxf(fmaxf(S[g][1][0], S[g][1][1]),              \
                                   fmaxf(S[g][1][2], S[g][1][3])));            \
            float mx2 = fmaxf(fmaxf(fmaxf(S[g][2][0], S[g][2][1]),             \
                                    fmaxf(S[g][2][2], S[g][2][3])),            \
                              fmaxf(fmaxf(S[g][3][0], S[g][3][1]),             \
                                    fmaxf(S[g][3][2], S[g][3][3])));           \
            mx = fmaxf(mx, mx2);                                               \
            mx = fmaxf(mx, __shfl_xor(mx, 16));                                \
            mx = fmaxf(mx, __shfl_xor(mx, 32));                                \
            float nm = fmaxf(m_i[g], mx);                                      \
            float alpha = __builtin_amdgcn_exp2f(m_i[g] - nm);                 \
            float rs = 0.0f;                                                   \
            _Pragma("unroll")                                                  \
            for (int kt = 0; kt < 4; ++kt) {                                   \
                float p0 = __builtin_amdgcn_exp2f(S[g][kt][0] - nm);           \
                float p1 = __builtin_amdgcn_exp2f(S[g][kt][1] - nm);           \
                float p2 = __builtin_amdgcn_exp2f(S[g][kt][2] - nm);           \
                float p3 = __builtin_amdgcn_exp2f(S[g][kt][3] - nm);           \
                rs += (p0 + p1) + (p2 + p3);                                   \
                pk16x2 lo = __builtin_amdgcn_cvt_pkrtz(p0, p1);                \
                pk16x2 hi = __builtin_amdgcn_cvt_pkrtz(p2, p3);                \
                half4 pk;                                                      \
                pk[0] = (_Float16)lo[0]; pk[1] = (_Float16)lo[1];              \
                pk[2] = (_Float16)hi[0]; pk[3] = (_Float16)hi[1];              \
                pfrag[g][kt] = pk;                                             \
            }                                                                  \
            rs += __shfl_xor(rs, 16);                                          \
            rs += __shfl_xor(rs, 32);                                          \
            l_i[g] = l_i[g] * alpha + rs;                                      \
            m_i[g] = nm;                                                       \
            _Pragma("unroll")                                                  \
            for (int nt = 0; nt < 4; ++nt) acc[g][nt] *= alpha;                \
        }                                                                      \
        _Pragma("unroll")                                                      \
        for (int kt = 0; kt < 4; ++kt) {                                       \
            _Pragma("unroll")                                                  \
            for (int nt = 0; nt < 4; ++nt) {                                   \
                const _Float16* vr = (VB) + (l15 + 16 * nt) * 64               \
                    + (((2 * kt + (quad >> 1)) ^ ksw) * 8) + (quad & 1) * 4;   \
                half4 vf = *(const half4*)vr;                                  \
                acc[0][nt] = mfma_k16(vf, pfrag[0][kt], acc[0][nt]);           \
                acc[1][nt] = mfma_k16(vf, pfrag[1][kt], acc[1][nt]);           \
            }                                                                  \
        }                                                                      \
    } while (0)

    STAGE(0, Ksm0, Vsm0);
    for (int kt = 0; kt < NKT; kt += 2) {
        __syncthreads();
        if (kt + 1 < NKT) STAGE(kt + 1, Ksm1, Vsm1);
        COMPUTE(Ksm0, Vsm0);
        __syncthreads();
        if (kt + 2 < NKT) STAGE(kt + 2, Ksm0, Vsm0);
        COMPUTE(Ksm1, Vsm1);
    }

    // ---- epilogue: transpose O^T through LDS, coalesced stores ----
    const int b = bh >> 2, h = bh & 3, ch0 = h * DH;
    floatx4 wp4 = *(const floatx4*)(wp + ch0 + l15 * 4);
    floatx4 bp4 = *(const floatx4*)(bp + ch0 + l15 * 4);
    float inv_l[2];
    #pragma unroll
    for (int g = 0; g < 2; ++g) inv_l[g] = 1.0f / l_i[g];

    __syncthreads();
    float* Ot = (float*)(pool) + wave * 2304;   // [32 q][72] floats, 9216B/wave
    #pragma unroll
    for (int g = 0; g < 2; ++g) {
        #pragma unroll
        for (int nt = 0; nt < 4; ++nt) {
            floatx4 o;
            #pragma unroll
            for (int r = 0; r < 4; ++r) o[r] = acc[g][nt][r] * inv_l[g];
            *(floatx4*)&Ot[(g * 16 + l15) * 72 + nt * 16 + quad * 4] = o;
        }
    }
    #pragma unroll
    for (int i = 0; i < 8; ++i) {
        int q = i * 4 + quad;
        floatx4 v = *(const floatx4*)&Ot[q * 72 + l15 * 4];
        floatx4 o;
        o.x = v.x * wp4.x + bp4.x;
        o.y = v.y * wp4.y + bp4.y;
        o.z = v.z * wp4.z + bp4.z;
        o.w = v.w * wp4.w + bp4.w;
        *(floatx4*)(out + ((size_t)b * HW + q0 + q) * CCH + ch0 + l15 * 4) = o;
    }
    #undef STAGE
    #undef COMPUTE
}

extern "C" void kernel_launch(void* const* d_in, const int* in_sizes, int n_in,
                              void* d_out, int out_size, void* d_ws, size_t ws_size,
                              hipStream_t stream) {
    const float* q_in = (const float*)d_in[0];
    const float* k_in = (const float*)d_in[1];
    const float* v_in = (const float*)d_in[2];
    const float* wq = (const float*)d_in[3];
    const float* bq = (const float*)d_in[4];
    const float* wk = (const float*)d_in[5];
    const float* bk = (const float*)d_in[6];
    const float* wv = (const float*)d_in[7];
    const float* bv = (const float*)d_in[8];
    const float* wp = (const float*)d_in[9];
    const float* bp = (const float*)d_in[10];
    float* out = (float*)d_out;

    const size_t tensor_halves = (size_t)4 * NH * HW * DH;
    _Float16* Qhat = (_Float16*)d_ws;
    _Float16* Khat = Qhat + tensor_halves;
    _Float16* Vthat = Khat + tensor_halves;

    prepass_all<<<dim3(4096 + 1024), 256, 0, stream>>>(
        q_in, k_in, v_in, wq, bq, wk, bk, wv, bv, Qhat, Khat, Vthat);
    attn_kernel<<<dim3(HW / QTILE, 4 * NH), 256, 0, stream>>>(
        Qhat, Khat, Vthat, wp, bp, out);
}